// Round 9
// baseline (353.587 us; speedup 1.0000x reference)
//
#include <hip/hip_runtime.h>

// LSTM B=4096 T=336 I=21 H=50 OUT=24, fp32 in/out.
// Round 17: invert the TLP<->ILP trade. Wave-count trend is monotone
// (16w=225us, 13w=214, 8w+skew=204): wide barriers cost more than TLP
// buys. So: NT=256, 4 waves, TPW=4 -> ONE wave per SIMD, all latency
// hiding from intra-wave ILP (4 indep MFMA chains, 4 indep pointwise
// chains), barrier syncs only 4 waves. Per-SIMD work unchanged (4
// tile-cells = the quantum). One ds_read pair serves 4 tiles.
//   - ~250 live VGPRs -> __attribute__((amdgpu_waves_per_eu(1))) (cap
//     512). We WANT 1 wave/SIMD, so high VGPR is free. (R12/R13 lesson:
//     without the attr the allocator caps at 64 and spills 37 GB.)
//   - CH=4 (xp[4][4]=64 regs), NCH=84, NLD=6. setprio/phase-skew
//     removed (1 wave/SIMD: nothing to arbitrate).
//   - XP strictly after PW -> xp[s] consumed in REC before any XPROJ
//     write; R15's clobber bug structurally impossible.
//   - FC epilogue re-strided for NT=256 (384 tasks).
//   Pre-committed: spill -> abandon; clean+>=195us -> R11+fix is floor.
//   Numerics frozen (R16-verified): 2-limb fp16 weights pre-scaled for
//   exp2 activations, h single fp16 in LDS, c~ = 2log2e*c in register,
//   pads compute h=0 exactly. Expected absmax 0.00098.
// LDS (halves), conflict-free B-frag reads (const + lane*16B):
//   hbuf[buf2][kb8][col16][8]   : h, k=0..63 (units 0..49 valid, rest 0)
//   xC[buf2][s4][kb4][col16][8] : x, k=0..31 (i<21 valid, rest 0)

#define T_SEQ 336
#define I_IN  21
#define HID   50
#define O_OUT 24
#define MB    16
#define NT    256
#define TPW   4                      // tiles per wave (4 waves -> 16 tiles)
#define CH    4
#define NCH   84                     // 336 / 4
#define XELEM (CH * MB * I_IN)       // 1344 floats per chunk
#define NLD   6                      // ceil(1344 / 256)
#define XBUFH (CH * 4 * 16 * 8)      // 2048 halves per x chunk buffer

#define HIDX(buf, kb, n, j) ((((buf)*8 + (kb))*16 + (n))*8 + (j))
#define XIDX(s, kb, n, j)   ((((s)*4 + (kb))*16 + (n))*8 + (j))

#define K_LOG2E 1.44269504088896340736f
#define C2SCALE (2.f * K_LOG2E)

typedef _Float16 f16x8 __attribute__((ext_vector_type(8)));
typedef float    f32x4 __attribute__((ext_vector_type(4)));

#define MFMA16(A, B, C) __builtin_amdgcn_mfma_f32_16x16x32_f16((A), (B), (C), 0, 0, 0)

static __device__ __forceinline__ float frcp(float v) { return __builtin_amdgcn_rcpf(v); }
static __device__ __forceinline__ float ex2(float v)  { return __builtin_amdgcn_exp2f(v); }
// gates pre-scaled: i,f,o by -log2e ; g by +2*log2e ; c~ is pre-scaled
static __device__ __forceinline__ float sigm2(float g) { return frcp(1.f + ex2(g)); }
static __device__ __forceinline__ float tanh2(float g) {      // tanh(true arg)
    return __builtin_fmaf(-2.f, frcp(1.f + ex2(g)), 1.f);
}
static __device__ __forceinline__ float tanh2s(float g) {     // 2log2e*tanh(true arg)
    return __builtin_fmaf(-2.f * C2SCALE, frcp(1.f + ex2(g)), C2SCALE);
}

// xproj build for chunk c+1, slot sp, ALL tiles (one ds_read, 8 MFMA).
// Runs AFTER the REC that consumed xp[*][s] -> clobber-safe.
#define XPROJ_ALL(sp)                                                    \
    do {                                                                 \
        const f16x8 XN = *(const f16x8*)&xC[wb + (sp) * 512 + bfo];      \
        xp[0][(sp)] = MFMA16(Xh[0], XN, biasv[0]);                       \
        xp[1][(sp)] = MFMA16(Xh[1], XN, biasv[1]);                       \
        xp[2][(sp)] = MFMA16(Xh[2], XN, biasv[2]);                       \
        xp[3][(sp)] = MFMA16(Xh[3], XN, biasv[3]);                       \
        xp[0][(sp)] = MFMA16(Xl[0], XN, xp[0][(sp)]);                    \
        xp[1][(sp)] = MFMA16(Xl[1], XN, xp[1][(sp)]);                    \
        xp[2][(sp)] = MFMA16(Xl[2], XN, xp[2][(sp)]);                    \
        xp[3][(sp)] = MFMA16(Xl[3], XN, xp[3][(sp)]);                    \
    } while (0)

__global__ __launch_bounds__(NT) __attribute__((amdgpu_waves_per_eu(1)))
void lstm_mfma17(const float* __restrict__ x,
                 const float* __restrict__ W_ih,
                 const float* __restrict__ W_hh,
                 const float* __restrict__ b_ih,
                 const float* __restrict__ b_hh,
                 const float* __restrict__ W_fc,
                 const float* __restrict__ b_fc,
                 float* __restrict__ out)
{
    __shared__ _Float16 hbuf[2 * 8 * 16 * 8];   // 2048 halves = 4 KB
    __shared__ _Float16 xC[2 * XBUFH];          // 4096 halves = 8 KB

    const int tid  = threadIdx.x;
    const int lane = tid & 63;
    const int wv   = tid >> 6;        // 0..3
    const int nl   = lane & 15;       // A: row-in-tile / B: batch col
    const int q    = lane >> 4;       // quad
    const int b0   = blockIdx.x * MB;

    // ---- zero-init LDS (pads must stay 0 forever; h(0)=0) ----
    for (int i = tid; i < 2 * 8 * 16 * 8; i += NT) hbuf[i] = (_Float16)0.f;
    for (int i = tid; i < 2 * XBUFH;      i += NT) xC[i]   = (_Float16)0.f;

    // ---- x staging precompute + issue chunk-0 loads ----
    // element e = tid + k*NT of a chunk: e = ((sI*16)+b)*21 + i
    const float* px[NLD];
    int  xdst[NLD];
    bool xv[NLD];
    float sv[NLD];
    #pragma unroll
    for (int k = 0; k < NLD; ++k) {
        const int e  = tid + k * NT;
        const int i  = e % I_IN;
        const int r  = e / I_IN;
        const int b  = r & 15;
        const int sIr = r >> 4;
        const int sI = (sIr < CH) ? sIr : 0;   // clamp tail (write is guarded)
        xv[k]   = (e < XELEM);
        px[k]   = x + ((size_t)(b0 + b) * T_SEQ + sI) * I_IN + i;
        xdst[k] = XIDX(sI, i >> 3, b, i & 7);
        sv[k]   = px[k][0];            // chunk 0 (overlaps weight build)
    }

    // ---- weights: 2-limb fp16 fragments + bias, built once, pre-scaled ----
    // A[m=nl][k]; packed row p = t*16+nl -> unit=p>>2, gate=p&3
    f16x8 Wh[TPW][2], Wl[TPW][2];   // W_hh, K-chunks 0,1 (k=0..63)
    f16x8 Xh[TPW],    Xl[TPW];      // W_ih, single K-chunk (k=0..31)
    f32x4 biasv[TPW];
    #pragma unroll
    for (int tt = 0; tt < TPW; ++tt) {
        const int t    = wv * TPW + tt;
        const int p    = t * 16 + nl;
        const int unit = p >> 2, gate = p & 3;
        const bool vr  = (unit < HID);
        const float ws = (gate == 2) ? C2SCALE : (-K_LOG2E);
        const int orig = gate * HID + unit;       // i,f,g,o stacked row
        const int ub   = t * 4 + q;               // unit for D rows q*4+r
        #pragma unroll
        for (int r = 0; r < 4; ++r) {
            const float bs = (r == 2) ? C2SCALE : (-K_LOG2E);
            biasv[tt][r] = (ub < HID) ? (b_ih[r * HID + ub] + b_hh[r * HID + ub]) * bs : 0.f;
        }
        #pragma unroll
        for (int kc = 0; kc < 2; ++kc) {
            #pragma unroll
            for (int j = 0; j < 8; ++j) {
                const int k = kc * 32 + q * 8 + j;
                const float w = (vr && k < HID) ? W_hh[orig * HID + k] * ws : 0.f;
                const _Float16 hi = (_Float16)w;
                Wh[tt][kc][j] = hi;
                Wl[tt][kc][j] = (_Float16)(w - (float)hi);
            }
        }
        #pragma unroll
        for (int j = 0; j < 8; ++j) {
            const int k = q * 8 + j;
            const float w = (vr && k < I_IN) ? W_ih[orig * I_IN + k] * ws : 0.f;
            const _Float16 hi = (_Float16)w;
            Xh[tt][j] = hi;
            Xl[tt][j] = (_Float16)(w - (float)hi);
        }
    }

    __syncthreads();   // zero-init visible (chunk-0 loads drained by sv use)

    // ---- commit chunk 0 into xC buf 0; advance pointers to chunk 1 ----
    #pragma unroll
    for (int k = 0; k < NLD; ++k) {
        if (xv[k]) xC[xdst[k]] = (_Float16)sv[k];
        px[k] += CH * I_IN;
    }
    __syncthreads();   // chunk-0 x visible

    // pointwise: lane owns units u = (wv*TPW+tt)*4+q for batch nl
    int hwo[TPW];
    float cst[TPW];
    #pragma unroll
    for (int tt = 0; tt < TPW; ++tt) {
        const int u = (wv * TPW + tt) * 4 + q;
        hwo[tt] = ((u >> 3) * 16 + nl) * 8 + (u & 7);   // + buf*1024
        cst[tt] = 0.f;    // scaled cell state c~ = 2log2e * c
    }

    const _Float16* hb0 = &hbuf[HIDX(0, q, nl, 0)];
    const int bfo = ((q * 16) + nl) * 8;           // B-frag offset within step

    // ---- xp prologue: xproj+bias for chunk 0, in registers ----
    f32x4 xp[TPW][CH];
    {
        const int wb = 0;
        #pragma unroll
        for (int s = 0; s < CH; ++s) XPROJ_ALL(s);
    }

    for (int c = 0; c < NCH; ++c) {
        const int  rb    = (c & 1) * XBUFH;
        const int  wb    = ((c + 1) & 1) * XBUFH;
        const bool dostg = (c + 1) < NCH;
        (void)rb;
        #pragma unroll
        for (int s = 0; s < CH; ++s) {
            __syncthreads();   // hbuf[cur] (h) complete; xC staged

            // staging loads for next chunk: first thing after the barrier
            if (s == 0 && dostg) {
                #pragma unroll
                for (int k = 0; k < NLD; ++k) sv[k] = px[k][0];
            }

            const int cur = s & 1, nxt = cur ^ 1;

            // ---- h B-frags: 2 contiguous b128 reads, serve all 4 tiles ----
            const _Float16* hb = hb0 + cur * 1024;
            const f16x8 B0 = *(const f16x8*)(hb);
            const f16x8 B1 = *(const f16x8*)(hb + 512);

            // ---- REC: 4 independent 4-deep 2-limb chains (ILP) ----
            f32x4 a[TPW];
            #pragma unroll
            for (int tt = 0; tt < TPW; ++tt) a[tt] = xp[tt][s];
            #pragma unroll
            for (int tt = 0; tt < TPW; ++tt) a[tt] = MFMA16(Wh[tt][0], B0, a[tt]);
            #pragma unroll
            for (int tt = 0; tt < TPW; ++tt) a[tt] = MFMA16(Wh[tt][1], B1, a[tt]);
            #pragma unroll
            for (int tt = 0; tt < TPW; ++tt) a[tt] = MFMA16(Wl[tt][0], B0, a[tt]);
            #pragma unroll
            for (int tt = 0; tt < TPW; ++tt) a[tt] = MFMA16(Wl[tt][1], B1, a[tt]);

            // ---- pointwise: 4 independent cells per lane (ILP) ----
            // (pad units: weights+bias 0 -> h computes to exactly 0)
            #pragma unroll
            for (int tt = 0; tt < TPW; ++tt) {
                const float tg2 = tanh2s(a[tt][2]);
                const float cc  = __builtin_fmaf(sigm2(a[tt][1]), cst[tt],
                                                 sigm2(a[tt][0]) * tg2);
                cst[tt] = cc;
                const float h = sigm2(a[tt][3]) * tanh2(cc);
                hbuf[nxt * 1024 + hwo[tt]] = (_Float16)h;
            }

            // ---- XP for chunk c+1 (off the critical path, clobber-safe) ----
            if (dostg && s >= 1) XPROJ_ALL(s - 1);
            if (dostg && s == CH - 1) XPROJ_ALL(CH - 1);

            // ---- commit staged x(next chunk) into the other x buffer ----
            if (s == 0 && dostg) {
                #pragma unroll
                for (int k = 0; k < NLD; ++k) {
                    if (xv[k]) xC[wb + xdst[k]] = (_Float16)sv[k];
                    px[k] += CH * I_IN;
                }
            }
        }
    }

    __syncthreads();
    // final h: t=335 -> s=3, wrote buf 0
    // ---- FC epilogue: 16*24 = 384 tasks over 256 threads (one-time) ----
    for (int t = tid; t < MB * O_OUT; t += NT) {
        const int b = t / O_OUT, o = t % O_OUT;
        float a = b_fc[o];
        for (int u = 0; u < HID; ++u) {
            const float hv = (float)hbuf[HIDX(0, u >> 3, b, u & 7)];
            a = __builtin_fmaf(hv, W_fc[o * HID + u], a);
        }
        out[(size_t)(b0 + b) * O_OUT + o] = a;
    }
}

extern "C" void kernel_launch(void* const* d_in, const int* in_sizes, int n_in,
                              void* d_out, int out_size, void* d_ws, size_t ws_size,
                              hipStream_t stream)
{
    const float* x    = (const float*)d_in[0];
    const float* W_ih = (const float*)d_in[1];
    const float* W_hh = (const float*)d_in[2];
    const float* b_ih = (const float*)d_in[3];
    const float* b_hh = (const float*)d_in[4];
    const float* W_fc = (const float*)d_in[5];
    const float* b_fc = (const float*)d_in[6];
    float* out = (float*)d_out;

    lstm_mfma17<<<dim3(4096 / MB), dim3(NT), 0, stream>>>(
        x, W_ih, W_hh, b_ih, b_hh, W_fc, b_fc, out);
}

// Round 10
// 322.194 us; speedup vs baseline: 1.0974x; 1.0974x over previous
//
#include <hip/hip_runtime.h>

// LSTM B=4096 T=336 I=21 H=50 OUT=24, fp32 in/out.
// Round 18 (FINAL): R11 structure + xp-clobber fix. Best-known config.
//   Config-space conclusion (R8-R17): wave-count curve is flat-bottomed
//   at 8 waves x TPW=2 + phase skew (204us). Pure-ILP (4w, 238), no-skew
//   (8w, 212; 13w, 214), and 4-wave-skew (16w, 225) all lose. Residual
//   gap to the issue-sum floor (~1035 cyc/step vs measured ~1460) is
//   barrier phase-convoy loss that 5 scheduling interventions could not
//   recover at HIP source level. Trans count (10/cell) is algorithmic;
//   MB=16 pinned by MFMA N=16 x 256 CUs; T-recurrence is serial.
//   FIX carried from R16 (bug introduced R11): for the XP-before-REC
//   phase group (ph==1), XPROJ(CH-1) at s==CH-1 clobbered xp[CH-1]
//   before the acc-init read -> last step of each chunk used next
//   chunk's x for those waves (absmax 0.0039). Snapshot a0i/a1i BEFORE
//   the ph==1 XP block. Verified numerics: absmax 0.00098 (R16/R17).
//   Structure: 256 wgs x 512 thr = 8 waves x 2 M-tiles (M padded 256).
//   Phase skew ph=(wv^(wv>>2))&1: group 1 runs XP before REC, group 0
//   after PW -> co-resident waves offset by ~80cyc of independent MFMA.
//   s_setprio(1) around REC. xproj off the h-path (xp[tile][s] f32 regs,
//   2-limb MFMA, bias as C-init, built for chunk c+1 during chunk c).
//   REC = pure W_hh GEMM K=64, merged 4-deep 2-limb chain per tile.
//   x staged per CH=8 chunk, double-buffered LDS. Weights 2 fp16 limbs
//   pre-scaled for exp2 activations (i,f,o x -log2e; g x 2log2e).
//   h single fp16 in LDS; scaled cell state c~ = 2log2e*c in register;
//   pads (units 50..63) have zero weights+bias -> compute h=0 exactly,
//   pointwise runs unguarded.
// LDS (halves), conflict-free B-frag reads (const + lane*16B):
//   hbuf[buf2][kb8][col16][8]   : h, k=0..63 (units 0..49 valid, rest 0)
//   xC[buf2][s8][kb4][col16][8] : x, k=0..31 (i<21 valid, rest 0)

#define T_SEQ 336
#define I_IN  21
#define HID   50
#define O_OUT 24
#define MB    16
#define NT    512
#define TPW   2                      // tiles per wave (8 waves -> 16 tiles)
#define CH    8
#define NCH   42                     // 336 / 8
#define XELEM (CH * MB * I_IN)       // 2688 floats per chunk
#define NLD   6                      // ceil(2688 / 512)
#define XBUFH (CH * 4 * 16 * 8)      // 4096 halves per x chunk buffer

#define HIDX(buf, kb, n, j) ((((buf)*8 + (kb))*16 + (n))*8 + (j))
#define XIDX(s, kb, n, j)   ((((s)*4 + (kb))*16 + (n))*8 + (j))

#define K_LOG2E 1.44269504088896340736f
#define C2SCALE (2.f * K_LOG2E)

typedef _Float16 f16x8 __attribute__((ext_vector_type(8)));
typedef float    f32x4 __attribute__((ext_vector_type(4)));

#define MFMA16(A, B, C) __builtin_amdgcn_mfma_f32_16x16x32_f16((A), (B), (C), 0, 0, 0)

static __device__ __forceinline__ float frcp(float v) { return __builtin_amdgcn_rcpf(v); }
static __device__ __forceinline__ float ex2(float v)  { return __builtin_amdgcn_exp2f(v); }
// gates pre-scaled: i,f,o by -log2e ; g by +2*log2e ; c~ is pre-scaled
static __device__ __forceinline__ float sigm2(float g) { return frcp(1.f + ex2(g)); }
static __device__ __forceinline__ float tanh2(float g) {      // tanh(true arg)
    return __builtin_fmaf(-2.f, frcp(1.f + ex2(g)), 1.f);
}
static __device__ __forceinline__ float tanh2s(float g) {     // 2log2e*tanh(true arg)
    return __builtin_fmaf(-2.f * C2SCALE, frcp(1.f + ex2(g)), C2SCALE);
}

// xproj build for chunk c+1, slot sp (compile-time in unrolled loop)
#define XPROJ(sp)                                                        \
    do {                                                                 \
        const f16x8 XN = *(const f16x8*)&xC[wb + (sp) * 512 + bfo];      \
        xp[0][(sp)] = MFMA16(Xh[0], XN, biasv[0]);                       \
        xp[0][(sp)] = MFMA16(Xl[0], XN, xp[0][(sp)]);                    \
        xp[1][(sp)] = MFMA16(Xh[1], XN, biasv[1]);                       \
        xp[1][(sp)] = MFMA16(Xl[1], XN, xp[1][(sp)]);                    \
    } while (0)

// per-step xproj schedule (slot s-1 at s=1..CH-1, +slot CH-1 at s=CH-1).
// Safe anywhere in the step body ONLY because a0i/a1i snapshot xp[*][s]
// first (the s==CH-1 XPROJ clobbers xp[CH-1] for the next chunk).
#define XPBLOCK()                                                        \
    do {                                                                 \
        if (dostg && s >= 1) XPROJ(s - 1);                               \
        if (dostg && s == CH - 1) XPROJ(CH - 1);                         \
    } while (0)

__global__ __launch_bounds__(NT)
void lstm_mfma18(const float* __restrict__ x,
                 const float* __restrict__ W_ih,
                 const float* __restrict__ W_hh,
                 const float* __restrict__ b_ih,
                 const float* __restrict__ b_hh,
                 const float* __restrict__ W_fc,
                 const float* __restrict__ b_fc,
                 float* __restrict__ out)
{
    __shared__ _Float16 hbuf[2 * 8 * 16 * 8];   // 2048 halves = 4 KB
    __shared__ _Float16 xC[2 * XBUFH];          // 8192 halves = 16 KB

    const int tid  = threadIdx.x;
    const int lane = tid & 63;
    const int wv   = tid >> 6;        // 0..7
    const int nl   = lane & 15;       // A: row-in-tile / B: batch col
    const int q    = lane >> 4;       // quad
    const int b0   = blockIdx.x * MB;
    const int ph   = (wv ^ (wv >> 2)) & 1;   // phase group (one of each per SIMD)

    // ---- zero-init LDS (pads must stay 0 forever; h(0)=0) ----
    for (int i = tid; i < 2 * 8 * 16 * 8; i += NT) hbuf[i] = (_Float16)0.f;
    for (int i = tid; i < 2 * XBUFH;      i += NT) xC[i]   = (_Float16)0.f;

    // ---- x staging precompute + issue chunk-0 loads ----
    // element e = tid + k*NT of a chunk: e = ((sI*16)+b)*21 + i
    const float* px[NLD];
    int  xdst[NLD];
    bool xv[NLD];
    float sv[NLD];
    #pragma unroll
    for (int k = 0; k < NLD; ++k) {
        const int e  = tid + k * NT;
        const int i  = e % I_IN;
        const int r  = e / I_IN;
        const int b  = r & 15;
        const int sIr = r >> 4;
        const int sI = (sIr < CH) ? sIr : 0;   // clamp tail (write is guarded)
        xv[k]   = (e < XELEM);
        px[k]   = x + ((size_t)(b0 + b) * T_SEQ + sI) * I_IN + i;
        xdst[k] = XIDX(sI, i >> 3, b, i & 7);
        sv[k]   = px[k][0];            // chunk 0 (overlaps weight build)
    }

    // ---- weights: 2-limb fp16 fragments + bias, built once, pre-scaled ----
    // A[m=nl][k]; packed row p = t*16+nl -> unit=p>>2, gate=p&3
    f16x8 Wh[TPW][2], Wl[TPW][2];   // W_hh, K-chunks 0,1 (k=0..63)
    f16x8 Xh[TPW],    Xl[TPW];      // W_ih, single K-chunk (k=0..31)
    f32x4 biasv[TPW];
    #pragma unroll
    for (int tt = 0; tt < TPW; ++tt) {
        const int t    = wv * TPW + tt;
        const int p    = t * 16 + nl;
        const int unit = p >> 2, gate = p & 3;
        const bool vr  = (unit < HID);
        const float ws = (gate == 2) ? C2SCALE : (-K_LOG2E);
        const int orig = gate * HID + unit;       // i,f,g,o stacked row
        const int ub   = t * 4 + q;               // unit for D rows q*4+r
        #pragma unroll
        for (int r = 0; r < 4; ++r) {
            const float bs = (r == 2) ? C2SCALE : (-K_LOG2E);
            biasv[tt][r] = (ub < HID) ? (b_ih[r * HID + ub] + b_hh[r * HID + ub]) * bs : 0.f;
        }
        #pragma unroll
        for (int kc = 0; kc < 2; ++kc) {
            #pragma unroll
            for (int j = 0; j < 8; ++j) {
                const int k = kc * 32 + q * 8 + j;
                const float w = (vr && k < HID) ? W_hh[orig * HID + k] * ws : 0.f;
                const _Float16 hi = (_Float16)w;
                Wh[tt][kc][j] = hi;
                Wl[tt][kc][j] = (_Float16)(w - (float)hi);
            }
        }
        #pragma unroll
        for (int j = 0; j < 8; ++j) {
            const int k = q * 8 + j;
            const float w = (vr && k < I_IN) ? W_ih[orig * I_IN + k] * ws : 0.f;
            const _Float16 hi = (_Float16)w;
            Xh[tt][j] = hi;
            Xl[tt][j] = (_Float16)(w - (float)hi);
        }
    }

    __syncthreads();   // zero-init visible (chunk-0 loads drained by sv use)

    // ---- commit chunk 0 into xC buf 0; advance pointers to chunk 1 ----
    #pragma unroll
    for (int k = 0; k < NLD; ++k) {
        if (xv[k]) xC[xdst[k]] = (_Float16)sv[k];
        px[k] += CH * I_IN;
    }
    __syncthreads();   // chunk-0 x visible

    // pointwise: lane owns units u0,u1 = (2wv+tt)*4+q for batch nl
    const int u0 = (wv * TPW + 0) * 4 + q;
    const int u1 = (wv * TPW + 1) * 4 + q;
    const int hwo0 = ((u0 >> 3) * 16 + nl) * 8 + (u0 & 7);   // + buf*1024
    const int hwo1 = ((u1 >> 3) * 16 + nl) * 8 + (u1 & 7);
    float cst0 = 0.f, cst1 = 0.f;    // scaled cell state c~ = 2log2e * c

    const _Float16* hb0 = &hbuf[HIDX(0, q, nl, 0)];
    const int bfo = ((q * 16) + nl) * 8;           // B-frag offset within step

    // ---- xp prologue: xproj+bias for chunk 0, in registers ----
    f32x4 xp[TPW][CH];
    {
        const int wb = 0;
        #pragma unroll
        for (int s = 0; s < CH; ++s) XPROJ(s);
    }

    for (int c = 0; c < NCH; ++c) {
        const int  rb    = (c & 1) * XBUFH;
        const int  wb    = ((c + 1) & 1) * XBUFH;
        const bool dostg = (c + 1) < NCH;
        #pragma unroll
        for (int s = 0; s < CH; ++s) {
            __syncthreads();   // hbuf[cur] (h) complete; xC[rb]/[wb] staged

            // staging loads for next chunk: first thing after the barrier
            if (s == 0 && dostg) {
                #pragma unroll
                for (int k = 0; k < NLD; ++k) sv[k] = px[k][0];
            }

            const int cur = s & 1, nxt = cur ^ 1;

            // ---- h B-frags: 2 contiguous b128 reads (critical path) ----
            const _Float16* hb = hb0 + cur * 1024;
            const f16x8 B0 = *(const f16x8*)(hb);
            const f16x8 B1 = *(const f16x8*)(hb + 512);

            // ---- BUGFIX (R16): snapshot xp[*][s] BEFORE any XPROJ can
            //      clobber it (ph==1 at s==CH-1 overwrites xp[CH-1]) ----
            const f32x4 a0i = xp[0][s];
            const f32x4 a1i = xp[1][s];

            // ---- phase group 1: xproj BEFORE recurrent (phase shifter) ----
            if (ph) XPBLOCK();

            // ---- recurrent MFMA: 2 merged 4-deep 2-limb chains ----
            __builtin_amdgcn_s_setprio(1);
            f32x4 a0 = a0i;
            f32x4 a1 = a1i;
            a0 = MFMA16(Wh[0][0], B0, a0);
            a1 = MFMA16(Wh[1][0], B0, a1);
            a0 = MFMA16(Wh[0][1], B1, a0);
            a1 = MFMA16(Wh[1][1], B1, a1);
            a0 = MFMA16(Wl[0][0], B0, a0);
            a1 = MFMA16(Wl[1][0], B0, a1);
            a0 = MFMA16(Wl[0][1], B1, a0);
            a1 = MFMA16(Wl[1][1], B1, a1);
            __builtin_amdgcn_s_setprio(0);

            // ---- pointwise cell updates, in registers, unguarded ----
            // (pad units: weights+bias 0 -> h computes to exactly 0)
            {
                const float tg2 = tanh2s(a0[2]);
                const float cc  = __builtin_fmaf(sigm2(a0[1]), cst0,
                                                 sigm2(a0[0]) * tg2);
                cst0 = cc;
                const float h = sigm2(a0[3]) * tanh2(cc);
                hbuf[nxt * 1024 + hwo0] = (_Float16)h;
            }
            {
                const float tg2 = tanh2s(a1[2]);
                const float cc  = __builtin_fmaf(sigm2(a1[1]), cst1,
                                                 sigm2(a1[0]) * tg2);
                cst1 = cc;
                const float h = sigm2(a1[3]) * tanh2(cc);
                hbuf[nxt * 1024 + hwo1] = (_Float16)h;
            }

            // ---- phase group 0: xproj AFTER pointwise ----
            if (!ph) XPBLOCK();

            // ---- commit staged x(next chunk) into the other x buffer ----
            if (s == 0 && dostg) {
                #pragma unroll
                for (int k = 0; k < NLD; ++k) {
                    if (xv[k]) xC[wb + xdst[k]] = (_Float16)sv[k];
                    px[k] += CH * I_IN;
                }
            }
        }
    }

    __syncthreads();
    // final h: t=335 -> s=7, wrote buf 0
    // ---- FC epilogue: 16*24 = 384 tasks (one-time) ----
    if (tid < MB * O_OUT) {
        const int b = tid / O_OUT, o = tid % O_OUT;
        float a = b_fc[o];
        for (int u = 0; u < HID; ++u) {
            const float hv = (float)hbuf[HIDX(0, u >> 3, b, u & 7)];
            a = __builtin_fmaf(hv, W_fc[o * HID + u], a);
        }
        out[(size_t)(b0 + b) * O_OUT + o] = a;
    }
}

extern "C" void kernel_launch(void* const* d_in, const int* in_sizes, int n_in,
                              void* d_out, int out_size, void* d_ws, size_t ws_size,
                              hipStream_t stream)
{
    const float* x    = (const float*)d_in[0];
    const float* W_ih = (const float*)d_in[1];
    const float* W_hh = (const float*)d_in[2];
    const float* b_ih = (const float*)d_in[3];
    const float* b_hh = (const float*)d_in[4];
    const float* W_fc = (const float*)d_in[5];
    const float* b_fc = (const float*)d_in[6];
    float* out = (float*)d_out;

    lstm_mfma18<<<dim3(4096 / MB), dim3(NT), 0, stream>>>(
        x, W_ih, W_hh, b_ih, b_hh, W_fc, b_fc, out);
}